// Round 2
// baseline (421.633 us; speedup 1.0000x reference)
//
#include <hip/hip_runtime.h>
#include <hip/hip_bf16.h>
#include <stdint.h>

#define HN 16      // heads
#define TT 2048    // seq len (T == S)
#define BBATCH 2
#define EE 1024
#define HD 64
#define MM 4096    // TT*BBATCH

typedef __attribute__((ext_vector_type(8))) __bf16 bfrag;
typedef __attribute__((ext_vector_type(4))) float f32x4;

__device__ __forceinline__ void gll16(const void* g, void* lds) {
  __builtin_amdgcn_global_load_lds(
      (const __attribute__((address_space(1))) void*)g,
      (__attribute__((address_space(3))) void*)lds, 16, 0, 0);
}

__device__ __forceinline__ f32x4 mfma_bf16(bfrag a, bfrag b, f32x4 c) {
  return __builtin_amdgcn_mfma_f32_16x16x32_bf16(a, b, c, 0, 0, 0);
}

// ---------------- fp32 -> bf16 conversion (7 tensors in one launch) -------
struct CvtArgs {
  const float* src[7];
  __bf16* dst[7];
  int n4[7];
};

__global__ __launch_bounds__(256) void cvt_all(CvtArgs a) {
  const int z = blockIdx.z;
  const int i = blockIdx.x * 256 + threadIdx.x;
  if (i < a.n4[z]) {
    float4 v = ((const float4*)a.src[z])[i];
    struct alignas(8) B4 { __bf16 a0, a1, a2, a3; };
    B4 o = {(__bf16)v.x, (__bf16)v.y, (__bf16)v.z, (__bf16)v.w};
    ((B4*)a.dst[z])[i] = o;
  }
}

// ---------------- GEMM: C(MMxEE) = X(MMxEE) * W(EExEE)^T + bias ----------
// 128x128 tile, BK=32, 256 threads (2x2 waves, 64x64 per wave, 4x4 frags).
// mode 0: bf16 out at ((b*HN+h)*TT + t)*HD + d        (t=m>>1, b=m&1)
// mode 2: bf16 out (V transposed) ((b*HN+h)*HD+d)*TT+s
__device__ __forceinline__ void gemm_core(const __bf16* __restrict__ X,
                                          const __bf16* __restrict__ W,
                                          const float* __restrict__ bias,
                                          void* __restrict__ out, int mode) {
  __shared__ __bf16 As[128 * 32];
  __shared__ __bf16 Bs[128 * 32];
  const int tid = threadIdx.x;
  const int lane = tid & 63, wave = tid >> 6;
  const int wm = wave >> 1, wn = wave & 1;
  const int quad = lane >> 4, l16 = lane & 15;
  const int m0 = blockIdx.y * 128, n0 = blockIdx.x * 128;
  const int srow = lane >> 2;          // 0..15 (16 rows per 1KB chunk)
  const int scol = (lane & 3) * 8;     // element col within BK=32
  const int c0 = 2 * wave;

  f32x4 acc[4][4] = {};

  for (int k0 = 0; k0 < EE; k0 += 32) {
    #pragma unroll
    for (int c = 0; c < 2; ++c) {
      const int ch = c0 + c;
      gll16(X + (size_t)(m0 + ch * 16 + srow) * EE + k0 + scol, As + ch * 512);
      gll16(W + (size_t)(n0 + ch * 16 + srow) * EE + k0 + scol, Bs + ch * 512);
    }
    __syncthreads();
    bfrag a[4], b[4];
    #pragma unroll
    for (int f = 0; f < 4; ++f)
      a[f] = *(const bfrag*)(As + (wm * 64 + f * 16 + l16) * 32 + quad * 8);
    #pragma unroll
    for (int f = 0; f < 4; ++f)
      b[f] = *(const bfrag*)(Bs + (wn * 64 + f * 16 + l16) * 32 + quad * 8);
    #pragma unroll
    for (int fm = 0; fm < 4; ++fm)
      #pragma unroll
      for (int fn = 0; fn < 4; ++fn)
        acc[fm][fn] = mfma_bf16(a[fm], b[fn], acc[fm][fn]);
    __syncthreads();
  }

  float bv[4];
  #pragma unroll
  for (int fn = 0; fn < 4; ++fn) bv[fn] = bias[n0 + wn * 64 + fn * 16 + l16];

  #pragma unroll
  for (int fm = 0; fm < 4; ++fm) {
    #pragma unroll
    for (int r = 0; r < 4; ++r) {
      const int gm = m0 + wm * 64 + fm * 16 + quad * 4 + r;
      #pragma unroll
      for (int fn = 0; fn < 4; ++fn) {
        const int gn = n0 + wn * 64 + fn * 16 + l16;
        const float v = acc[fm][fn][r] + bv[fn];
        if (mode == 0) {
          const int t = gm >> 1, bb = gm & 1, h = gn >> 6, d = gn & 63;
          ((__bf16*)out)[(((size_t)(bb * HN + h)) * TT + t) * HD + d] = (__bf16)v;
        } else {
          const int s = gm >> 1, bb = gm & 1, h = gn >> 6, d = gn & 63;
          ((__bf16*)out)[(((size_t)(bb * HN + h)) * HD + d) * TT + s] = (__bf16)v;
        }
      }
    }
  }
}

__global__ __launch_bounds__(256) void gemm_qkv(
    const __bf16* __restrict__ xq, const __bf16* __restrict__ xk,
    const __bf16* __restrict__ xv, const __bf16* __restrict__ wq,
    const __bf16* __restrict__ wk, const __bf16* __restrict__ wv,
    const float* __restrict__ bq, const float* __restrict__ bk,
    const float* __restrict__ bv, __bf16* __restrict__ qo,
    __bf16* __restrict__ ko, __bf16* __restrict__ vo) {
  const __bf16 *X, *W;
  const float* bias;
  __bf16* out;
  int mode;
  if (blockIdx.z == 0)      { X = xq; W = wq; bias = bq; out = qo; mode = 0; }
  else if (blockIdx.z == 1) { X = xk; W = wk; bias = bk; out = ko; mode = 0; }
  else                      { X = xv; W = wv; bias = bv; out = vo; mode = 2; }
  gemm_core(X, W, bias, out, mode);
}

// ---- output GEMM: 64x128 tile for 512 blocks (2/CU instead of 1/CU) -----
__global__ __launch_bounds__(256) void gemm_o64(const __bf16* __restrict__ X,
                                                const __bf16* __restrict__ W,
                                                const float* __restrict__ bias,
                                                float* __restrict__ out) {
  __shared__ __bf16 As[64 * 32];
  __shared__ __bf16 Bs[128 * 32];
  const int tid = threadIdx.x;
  const int lane = tid & 63, wave = tid >> 6;   // wave 0..3 = n-split
  const int quad = lane >> 4, l16 = lane & 15;
  const int m0 = blockIdx.y * 64, n0 = blockIdx.x * 128;
  const int srow = lane >> 2, scol = (lane & 3) * 8;

  f32x4 acc[4][2] = {};

  for (int k0 = 0; k0 < EE; k0 += 32) {
    gll16(X + (size_t)(m0 + wave * 16 + srow) * EE + k0 + scol, As + wave * 512);
    #pragma unroll
    for (int c = 0; c < 2; ++c) {
      const int ch = 2 * wave + c;
      gll16(W + (size_t)(n0 + ch * 16 + srow) * EE + k0 + scol, Bs + ch * 512);
    }
    __syncthreads();
    bfrag a[4], b2[2];
    #pragma unroll
    for (int f = 0; f < 4; ++f)
      a[f] = *(const bfrag*)(As + (f * 16 + l16) * 32 + quad * 8);
    #pragma unroll
    for (int f = 0; f < 2; ++f)
      b2[f] = *(const bfrag*)(Bs + (wave * 32 + f * 16 + l16) * 32 + quad * 8);
    #pragma unroll
    for (int fm = 0; fm < 4; ++fm)
      #pragma unroll
      for (int fn = 0; fn < 2; ++fn)
        acc[fm][fn] = mfma_bf16(a[fm], b2[fn], acc[fm][fn]);
    __syncthreads();
  }

  float bv[2];
  #pragma unroll
  for (int fn = 0; fn < 2; ++fn) bv[fn] = bias[n0 + wave * 32 + fn * 16 + l16];

  #pragma unroll
  for (int fm = 0; fm < 4; ++fm)
    #pragma unroll
    for (int r = 0; r < 4; ++r) {
      const int gm = m0 + fm * 16 + quad * 4 + r;
      #pragma unroll
      for (int fn = 0; fn < 2; ++fn) {
        const int gn = n0 + wave * 32 + fn * 16 + l16;
        out[(size_t)gm * EE + gn] = acc[fm][fn][r] + bv[fn];
      }
    }
}

// ---------------- flash attention fwd: O (normalized) + linv -------------
// t-tile 64, grid (TT/64, HN, BBATCH) = 1024 blocks. 4 waves (2x2).
// Q frags register-resident; K/VT frags direct from global (16B contiguous);
// LDS only for the P C->A layout round-trip, padded stride 72.
__global__ __launch_bounds__(256) void attn_fwd(const __bf16* __restrict__ qb,
                                                const __bf16* __restrict__ kb,
                                                const __bf16* __restrict__ vtb,
                                                __bf16* __restrict__ ob,
                                                float* __restrict__ linv_ws) {
  __shared__ __bf16 Ps[64 * 72];   // padded: stride 144B (16B-aligned, 4-way max)
  __shared__ float Lred[2][64];
  __shared__ float LinvS[64];

  const int tid = threadIdx.x, lane = tid & 63, wave = tid >> 6;
  const int wm = wave >> 1, wn = wave & 1;
  const int quad = lane >> 4, l16 = lane & 15;
  const int t0 = blockIdx.x * 64;
  const int h = blockIdx.y, b = blockIdx.z;
  const size_t bh = (size_t)(b * HN + h);

  const __bf16* qbase = qb + bh * TT * HD;
  const __bf16* kbase = kb + bh * TT * HD;
  const __bf16* vbase = vtb + bh * HD * TT;

  // Q fragments: loop-invariant, load once. A[m = t0+wm*32+f*16+l16][k]
  bfrag qf[2][2];
  #pragma unroll
  for (int f = 0; f < 2; ++f)
    #pragma unroll
    for (int ks = 0; ks < 2; ++ks)
      qf[f][ks] = *(const bfrag*)(qbase + (size_t)(t0 + wm * 32 + f * 16 + l16) * HD +
                                  ks * 32 + quad * 8);

  f32x4 oacc[2][2] = {};
  float lpart[2][4] = {};

  for (int s0 = 0; s0 < TT; s0 += 64) {
    // ---- scores: 64t x 64s, wave tile 32x32 (2x2 frags)
    f32x4 sacc[2][2] = {};
    #pragma unroll
    for (int ks = 0; ks < 2; ++ks) {
      bfrag kf[2];
      #pragma unroll
      for (int f = 0; f < 2; ++f)
        kf[f] = *(const bfrag*)(kbase + (size_t)(s0 + wn * 32 + f * 16 + l16) * HD +
                                ks * 32 + quad * 8);
      #pragma unroll
      for (int fm = 0; fm < 2; ++fm)
        #pragma unroll
        for (int fn = 0; fn < 2; ++fn)
          sacc[fm][fn] = mfma_bf16(qf[fm][ks], kf[fn], sacc[fm][fn]);
    }

    // ---- p = exp(s/8); accumulate l; write P to LDS (C-layout -> A-layout)
    #pragma unroll
    for (int fm = 0; fm < 2; ++fm)
      #pragma unroll
      for (int fn = 0; fn < 2; ++fn)
        #pragma unroll
        for (int r = 0; r < 4; ++r) {
          const float p = __expf(sacc[fm][fn][r] * 0.125f);
          lpart[fm][r] += p;
          const int row = wm * 32 + fm * 16 + quad * 4 + r;
          const int col = wn * 32 + fn * 16 + l16;
          Ps[row * 72 + col] = (__bf16)p;
        }
    __syncthreads();

    // ---- O += P * V : 64t x 64d, wave tile 32x32; V frags direct global
    #pragma unroll
    for (int ks = 0; ks < 2; ++ks) {
      bfrag pf[2], vf[2];
      #pragma unroll
      for (int f = 0; f < 2; ++f)
        pf[f] = *(const bfrag*)(Ps + (wm * 32 + f * 16 + l16) * 72 + ks * 32 + quad * 8);
      #pragma unroll
      for (int f = 0; f < 2; ++f)
        vf[f] = *(const bfrag*)(vbase + (size_t)(wn * 32 + f * 16 + l16) * TT +
                                s0 + ks * 32 + quad * 8);
      #pragma unroll
      for (int fm = 0; fm < 2; ++fm)
        #pragma unroll
        for (int fn = 0; fn < 2; ++fn)
          oacc[fm][fn] = mfma_bf16(pf[fm], vf[fn], oacc[fm][fn]);
    }
    __syncthreads();
  }

  // ---- row-sum reduce: across 16 lanes (cols), then across wn waves
  #pragma unroll
  for (int fm = 0; fm < 2; ++fm)
    #pragma unroll
    for (int r = 0; r < 4; ++r) {
      float v = lpart[fm][r];
      v += __shfl_xor(v, 1, 16);
      v += __shfl_xor(v, 2, 16);
      v += __shfl_xor(v, 4, 16);
      v += __shfl_xor(v, 8, 16);
      lpart[fm][r] = v;
    }
  if (l16 == 0) {
    #pragma unroll
    for (int fm = 0; fm < 2; ++fm)
      #pragma unroll
      for (int r = 0; r < 4; ++r)
        Lred[wn][wm * 32 + fm * 16 + quad * 4 + r] = lpart[fm][r];
  }
  __syncthreads();
  if (tid < 64) {
    const float linv = 1.0f / (Lred[0][tid] + Lred[1][tid]);
    LinvS[tid] = linv;
    linv_ws[bh * TT + t0 + tid] = linv;
  }
  __syncthreads();

  #pragma unroll
  for (int fm = 0; fm < 2; ++fm)
    #pragma unroll
    for (int r = 0; r < 4; ++r) {
      const int row = wm * 32 + fm * 16 + quad * 4 + r;
      const float linv = LinvS[row];
      #pragma unroll
      for (int fn = 0; fn < 2; ++fn) {
        const int d = wn * 32 + fn * 16 + l16;
        ob[((size_t)(t0 + row) * BBATCH + b) * EE + h * HD + d] =
            (__bf16)(oacc[fm][fn][r] * linv);
      }
    }
}

// ---------------- avg_w: mean over heads of softmax probs ----------------
// Zero LDS, zero barriers. t-tile 128 x s-tile 64, waves 2x2 (wave 64t x 32s).
// grid (TT/64 s-tiles, TT/128 t-tiles, BBATCH) = 1024 blocks.
__global__ __launch_bounds__(256) void avg_attn(const __bf16* __restrict__ qb,
                                                const __bf16* __restrict__ kb,
                                                const float* __restrict__ linv_ws,
                                                float* __restrict__ avg_out) {
  const int tid = threadIdx.x, lane = tid & 63, wave = tid >> 6;
  const int wm = wave >> 1, wn = wave & 1;
  const int quad = lane >> 4, l16 = lane & 15;
  const int s0 = blockIdx.x * 64, t0 = blockIdx.y * 128;
  const int b = blockIdx.z;

  f32x4 aacc[4][2] = {};

  for (int h = 0; h < HN; ++h) {
    const size_t bh = (size_t)(b * HN + h);
    const __bf16* qbase = qb + bh * TT * HD;
    const __bf16* kbase = kb + bh * TT * HD;

    f32x4 sacc[4][2] = {};
    #pragma unroll
    for (int ks = 0; ks < 2; ++ks) {
      bfrag q4[4], k2[2];
      #pragma unroll
      for (int f = 0; f < 4; ++f)
        q4[f] = *(const bfrag*)(qbase + (size_t)(t0 + wm * 64 + f * 16 + l16) * HD +
                                ks * 32 + quad * 8);
      #pragma unroll
      for (int f = 0; f < 2; ++f)
        k2[f] = *(const bfrag*)(kbase + (size_t)(s0 + wn * 32 + f * 16 + l16) * HD +
                                ks * 32 + quad * 8);
      #pragma unroll
      for (int fm = 0; fm < 4; ++fm)
        #pragma unroll
        for (int fn = 0; fn < 2; ++fn)
          sacc[fm][fn] = mfma_bf16(q4[fm], k2[fn], sacc[fm][fn]);
    }

    float lr[4][4];
    #pragma unroll
    for (int fm = 0; fm < 4; ++fm)
      #pragma unroll
      for (int r = 0; r < 4; ++r)
        lr[fm][r] = linv_ws[bh * TT + t0 + wm * 64 + fm * 16 + quad * 4 + r];

    #pragma unroll
    for (int fm = 0; fm < 4; ++fm)
      #pragma unroll
      for (int fn = 0; fn < 2; ++fn)
        #pragma unroll
        for (int r = 0; r < 4; ++r)
          aacc[fm][fn][r] += __expf(sacc[fm][fn][r] * 0.125f) * lr[fm][r];
  }

  const float invh = 1.0f / (float)HN;
  #pragma unroll
  for (int fm = 0; fm < 4; ++fm)
    #pragma unroll
    for (int r = 0; r < 4; ++r) {
      const int t = t0 + wm * 64 + fm * 16 + quad * 4 + r;
      #pragma unroll
      for (int fn = 0; fn < 2; ++fn) {
        const int s = s0 + wn * 32 + fn * 16 + l16;
        avg_out[((size_t)b * TT + t) * TT + s] = aacc[fm][fn][r] * invh;
      }
    }
}

extern "C" void kernel_launch(void* const* d_in, const int* in_sizes, int n_in,
                              void* d_out, int out_size, void* d_ws, size_t ws_size,
                              hipStream_t stream) {
  (void)in_sizes; (void)n_in; (void)out_size; (void)ws_size;
  const float* query = (const float*)d_in[0];
  const float* key   = (const float*)d_in[1];
  const float* value = (const float*)d_in[2];
  const float* Wq = (const float*)d_in[3];
  const float* bq = (const float*)d_in[4];
  const float* Wk = (const float*)d_in[5];
  const float* bk = (const float*)d_in[6];
  const float* Wv = (const float*)d_in[7];
  const float* bv = (const float*)d_in[8];
  const float* Wo = (const float*)d_in[9];
  const float* bo = (const float*)d_in[10];

  char* ws = (char*)d_ws;
  size_t off = 0;
  auto wsalloc = [&](size_t bytes) -> void* {
    void* p = ws + off;
    off += (bytes + 255) & ~(size_t)255;
    return p;
  };
  const size_t XE = (size_t)MM * EE;        // 4,194,304 elems
  const size_t WE = (size_t)EE * EE;        // 1,048,576 elems
  __bf16* xq   = (__bf16*)wsalloc(XE * 2);
  __bf16* xk   = (__bf16*)wsalloc(XE * 2);
  __bf16* xv   = (__bf16*)wsalloc(XE * 2);
  __bf16* wqb  = (__bf16*)wsalloc(WE * 2);
  __bf16* wkb  = (__bf16*)wsalloc(WE * 2);
  __bf16* wvb  = (__bf16*)wsalloc(WE * 2);
  __bf16* wob  = (__bf16*)wsalloc(WE * 2);
  __bf16* qbuf = (__bf16*)wsalloc(XE * 2);
  __bf16* kbuf = (__bf16*)wsalloc(XE * 2);
  __bf16* vtbuf= (__bf16*)wsalloc(XE * 2);
  __bf16* obuf = (__bf16*)wsalloc(XE * 2);
  float* linv  = (float*)wsalloc((size_t)BBATCH * HN * TT * 4);
  // total ~64.3 MB of ws

  CvtArgs ca;
  ca.src[0] = query; ca.dst[0] = xq;  ca.n4[0] = (int)(XE / 4);
  ca.src[1] = key;   ca.dst[1] = xk;  ca.n4[1] = (int)(XE / 4);
  ca.src[2] = value; ca.dst[2] = xv;  ca.n4[2] = (int)(XE / 4);
  ca.src[3] = Wq;    ca.dst[3] = wqb; ca.n4[3] = (int)(WE / 4);
  ca.src[4] = Wk;    ca.dst[4] = wkb; ca.n4[4] = (int)(WE / 4);
  ca.src[5] = Wv;    ca.dst[5] = wvb; ca.n4[5] = (int)(WE / 4);
  ca.src[6] = Wo;    ca.dst[6] = wob; ca.n4[6] = (int)(WE / 4);
  cvt_all<<<dim3(4096, 1, 7), 256, 0, stream>>>(ca);

  gemm_qkv<<<dim3(8, 32, 3), 256, 0, stream>>>(xq, xk, xv, wqb, wkb, wvb,
                                               bq, bk, bv, qbuf, kbuf, vtbuf);

  attn_fwd<<<dim3(32, 16, 2), 256, 0, stream>>>(qbuf, kbuf, vtbuf, obuf, linv);

  float* avg_out = (float*)d_out + (size_t)TT * BBATCH * EE;
  avg_attn<<<dim3(32, 16, 2), 256, 0, stream>>>(qbuf, kbuf, linv, avg_out);

  gemm_o64<<<dim3(8, 64), 256, 0, stream>>>(obuf, wob, bo, (float*)d_out);
}

// Round 3
// 300.448 us; speedup vs baseline: 1.4033x; 1.4033x over previous
//
#include <hip/hip_runtime.h>
#include <hip/hip_bf16.h>
#include <stdint.h>

#define HN 16      // heads
#define TT 2048    // seq len (T == S)
#define BBATCH 2
#define EE 1024
#define HD 64
#define MM 4096    // TT*BBATCH

typedef __attribute__((ext_vector_type(8))) __bf16 bfrag;
typedef __attribute__((ext_vector_type(4))) float f32x4;

__device__ __forceinline__ void gll16(const void* g, void* lds) {
  __builtin_amdgcn_global_load_lds(
      (const __attribute__((address_space(1))) void*)g,
      (__attribute__((address_space(3))) void*)lds, 16, 0, 0);
}

__device__ __forceinline__ f32x4 mfma_bf16(bfrag a, bfrag b, f32x4 c) {
  return __builtin_amdgcn_mfma_f32_16x16x32_bf16(a, b, c, 0, 0, 0);
}

// ---- XOR-swizzled 64-elem-row LDS tiles -----------------------------------
// Row = 64 bf16 = 8 chunks of 16B. Logical chunk c of row r lives at phys
// chunk c^(r&7). Fragment b128 reads (16 l16-lanes, same chunk, rows +1)
// then spread over all 8 chunk columns -> 2-way bank aliasing = free.
// e must be a multiple of 8 (one chunk).
__device__ __forceinline__ const bfrag* fragp(const __bf16* base, int row, int e) {
  return (const bfrag*)(base + row * 64 + ((((e >> 3) ^ row) & 7) << 3));
}
// scalar element address in swizzled tile
__device__ __forceinline__ int swze(int row, int col) {
  return row * 64 + ((((col >> 3) ^ row) & 7) << 3) + (col & 7);
}
// Stage rows r0..r0+7 (r0 multiple of 8) of a 64-elem-row tile, swizzled,
// with one global_load_lds: lane i -> row r0+(i>>3), phys chunk i&7, which
// must hold logical chunk (i&7)^(i>>3) -> permute the GLOBAL fetch address.
__device__ __forceinline__ void stage8(const __bf16* grow0, int gstride,
                                       __bf16* tile, int r0, int lane) {
  const int rr = lane >> 3;
  const int cl = (lane & 7) ^ rr;
  gll16(grow0 + (size_t)(r0 + rr) * gstride + cl * 8, tile + r0 * 64);
}

// ---------------- fp32 -> bf16 conversion (7 tensors in one launch) -------
struct CvtArgs {
  const float* src[7];
  __bf16* dst[7];
  int n4[7];
};

__global__ __launch_bounds__(256) void cvt_all(CvtArgs a) {
  const int z = blockIdx.z;
  const int i = blockIdx.x * 256 + threadIdx.x;
  if (i < a.n4[z]) {
    float4 v = ((const float4*)a.src[z])[i];
    struct alignas(8) B4 { __bf16 a0, a1, a2, a3; };
    B4 o = {(__bf16)v.x, (__bf16)v.y, (__bf16)v.z, (__bf16)v.w};
    ((B4*)a.dst[z])[i] = o;
  }
}

// ---------------- GEMM: C(MMxEE) = X(MMxEE) * W(EExEE)^T + bias ----------
// 128x128 tile, BK=32, 256 threads (2x2 waves, 64x64 per wave, 4x4 frags).
__device__ __forceinline__ void gemm_core(const __bf16* __restrict__ X,
                                          const __bf16* __restrict__ W,
                                          const float* __restrict__ bias,
                                          void* __restrict__ out, int mode) {
  __shared__ __bf16 As[128 * 32];
  __shared__ __bf16 Bs[128 * 32];
  const int tid = threadIdx.x;
  const int lane = tid & 63, wave = tid >> 6;
  const int wm = wave >> 1, wn = wave & 1;
  const int quad = lane >> 4, l16 = lane & 15;
  const int m0 = blockIdx.y * 128, n0 = blockIdx.x * 128;
  const int srow = lane >> 2;          // 0..15 (16 rows per 1KB chunk)
  const int scol = (lane & 3) * 8;     // element col within BK=32
  const int c0 = 2 * wave;

  f32x4 acc[4][4] = {};

  for (int k0 = 0; k0 < EE; k0 += 32) {
    #pragma unroll
    for (int c = 0; c < 2; ++c) {
      const int ch = c0 + c;
      gll16(X + (size_t)(m0 + ch * 16 + srow) * EE + k0 + scol, As + ch * 512);
      gll16(W + (size_t)(n0 + ch * 16 + srow) * EE + k0 + scol, Bs + ch * 512);
    }
    __syncthreads();
    bfrag a[4], b[4];
    #pragma unroll
    for (int f = 0; f < 4; ++f)
      a[f] = *(const bfrag*)(As + (wm * 64 + f * 16 + l16) * 32 + quad * 8);
    #pragma unroll
    for (int f = 0; f < 4; ++f)
      b[f] = *(const bfrag*)(Bs + (wn * 64 + f * 16 + l16) * 32 + quad * 8);
    #pragma unroll
    for (int fm = 0; fm < 4; ++fm)
      #pragma unroll
      for (int fn = 0; fn < 4; ++fn)
        acc[fm][fn] = mfma_bf16(a[fm], b[fn], acc[fm][fn]);
    __syncthreads();
  }

  float bv[4];
  #pragma unroll
  for (int fn = 0; fn < 4; ++fn) bv[fn] = bias[n0 + wn * 64 + fn * 16 + l16];

  #pragma unroll
  for (int fm = 0; fm < 4; ++fm) {
    #pragma unroll
    for (int r = 0; r < 4; ++r) {
      const int gm = m0 + wm * 64 + fm * 16 + quad * 4 + r;
      #pragma unroll
      for (int fn = 0; fn < 4; ++fn) {
        const int gn = n0 + wn * 64 + fn * 16 + l16;
        const float v = acc[fm][fn][r] + bv[fn];
        if (mode == 0) {
          const int t = gm >> 1, bb = gm & 1, h = gn >> 6, d = gn & 63;
          ((__bf16*)out)[(((size_t)(bb * HN + h)) * TT + t) * HD + d] = (__bf16)v;
        } else {
          const int s = gm >> 1, bb = gm & 1, h = gn >> 6, d = gn & 63;
          ((__bf16*)out)[(((size_t)(bb * HN + h)) * HD + d) * TT + s] = (__bf16)v;
        }
      }
    }
  }
}

__global__ __launch_bounds__(256) void gemm_qkv(
    const __bf16* __restrict__ xq, const __bf16* __restrict__ xk,
    const __bf16* __restrict__ xv, const __bf16* __restrict__ wq,
    const __bf16* __restrict__ wk, const __bf16* __restrict__ wv,
    const float* __restrict__ bq, const float* __restrict__ bk,
    const float* __restrict__ bv, __bf16* __restrict__ qo,
    __bf16* __restrict__ ko, __bf16* __restrict__ vo) {
  const __bf16 *X, *W;
  const float* bias;
  __bf16* out;
  int mode;
  if (blockIdx.z == 0)      { X = xq; W = wq; bias = bq; out = qo; mode = 0; }
  else if (blockIdx.z == 1) { X = xk; W = wk; bias = bk; out = ko; mode = 0; }
  else                      { X = xv; W = wv; bias = bv; out = vo; mode = 2; }
  gemm_core(X, W, bias, out, mode);
}

// ---- output GEMM: 64x128 tile for 512 blocks ----------------------------
__global__ __launch_bounds__(256) void gemm_o64(const __bf16* __restrict__ X,
                                                const __bf16* __restrict__ W,
                                                const float* __restrict__ bias,
                                                float* __restrict__ out) {
  __shared__ __bf16 As[64 * 32];
  __shared__ __bf16 Bs[128 * 32];
  const int tid = threadIdx.x;
  const int lane = tid & 63, wave = tid >> 6;   // wave 0..3 = n-split
  const int quad = lane >> 4, l16 = lane & 15;
  const int m0 = blockIdx.y * 64, n0 = blockIdx.x * 128;
  const int srow = lane >> 2, scol = (lane & 3) * 8;

  f32x4 acc[4][2] = {};

  for (int k0 = 0; k0 < EE; k0 += 32) {
    gll16(X + (size_t)(m0 + wave * 16 + srow) * EE + k0 + scol, As + wave * 512);
    #pragma unroll
    for (int c = 0; c < 2; ++c) {
      const int ch = 2 * wave + c;
      gll16(W + (size_t)(n0 + ch * 16 + srow) * EE + k0 + scol, Bs + ch * 512);
    }
    __syncthreads();
    bfrag a[4], b2[2];
    #pragma unroll
    for (int f = 0; f < 4; ++f)
      a[f] = *(const bfrag*)(As + (f * 16 + l16) * 32 + quad * 8);
    #pragma unroll
    for (int f = 0; f < 2; ++f)
      b2[f] = *(const bfrag*)(Bs + (wave * 32 + f * 16 + l16) * 32 + quad * 8);
    #pragma unroll
    for (int fm = 0; fm < 4; ++fm)
      #pragma unroll
      for (int fn = 0; fn < 2; ++fn)
        acc[fm][fn] = mfma_bf16(a[fm], b2[fn], acc[fm][fn]);
    __syncthreads();
  }

  float bv[2];
  #pragma unroll
  for (int fn = 0; fn < 2; ++fn) bv[fn] = bias[n0 + wave * 32 + fn * 16 + l16];

  #pragma unroll
  for (int fm = 0; fm < 4; ++fm)
    #pragma unroll
    for (int r = 0; r < 4; ++r) {
      const int gm = m0 + fm * 16 + quad * 4 + r;
      #pragma unroll
      for (int fn = 0; fn < 2; ++fn) {
        const int gn = n0 + wave * 32 + fn * 16 + l16;
        out[(size_t)gm * EE + gn] = acc[fm][fn][r] + bv[fn];
      }
    }
}

// ---------------- flash attention fwd: O (normalized) + linv -------------
// t-tile 128, grid (16, HN, B) = 512 blocks, 4 waves. Wave w owns t rows
// [w*32, w*32+32) x ALL 64 s-cols -> P produced & consumed by same wave
// (no barrier), row-sums need no cross-wave reduce. K/V double-buffered via
// swizzled global_load_lds; ONE barrier per s-iter, prefetch in flight
// across the whole compute phase. Q LDS reused as P buffer (per-wave rows).
__global__ __launch_bounds__(256) void attn_fwd(const __bf16* __restrict__ qb,
                                                const __bf16* __restrict__ kb,
                                                const __bf16* __restrict__ vtb,
                                                __bf16* __restrict__ ob,
                                                float* __restrict__ linv_ws) {
  __shared__ __bf16 QP[128 * 64];      // Q tile, then P tile (16KB)
  __shared__ __bf16 Ks[2][64 * 64];    // 2 x 8KB
  __shared__ __bf16 Vs[2][64 * 64];    // 2 x 8KB

  const int tid = threadIdx.x, lane = tid & 63, w = tid >> 6;
  const int quad = lane >> 4, l16 = lane & 15;
  const int t0 = blockIdx.x * 128;
  const int h = blockIdx.y, b = blockIdx.z;
  const size_t bh = (size_t)(b * HN + h);

  const __bf16* qbase = qb + (bh * TT + t0) * HD;
  const __bf16* kbase = kb + bh * TT * HD;
  const __bf16* vbase = vtb + bh * HD * TT;

  // stage Q (rows w*32..w*32+31) and K/V for s0=0 (rows w*16..w*16+15)
  #pragma unroll
  for (int c = 0; c < 4; ++c) stage8(qbase, HD, QP, w * 32 + c * 8, lane);
  #pragma unroll
  for (int c = 0; c < 2; ++c) {
    stage8(kbase, HD, Ks[0], w * 16 + c * 8, lane);
    stage8(vbase + /*s0=*/0, TT, Vs[0], w * 16 + c * 8, lane);
  }
  __syncthreads();

  // Q fragments: loop-invariant (rows w*32 + f*16 + l16)
  bfrag qf[2][2];
  #pragma unroll
  for (int f = 0; f < 2; ++f)
    #pragma unroll
    for (int ks = 0; ks < 2; ++ks)
      qf[f][ks] = *fragp(QP, w * 32 + f * 16 + l16, ks * 32 + quad * 8);

  f32x4 oacc[2][4] = {};
  float lpart[2][4] = {};

  for (int it = 0; it < TT / 64; ++it) {
    const int cur = it & 1;
    if (it) __syncthreads();   // buf[cur] staged; frees buf[1-cur]
    if (it + 1 < TT / 64) {    // async prefetch, lands during compute
      const int s1 = (it + 1) * 64;
      #pragma unroll
      for (int c = 0; c < 2; ++c) {
        stage8(kbase + (size_t)s1 * HD, HD, Ks[1 - cur], w * 16 + c * 8, lane);
        stage8(vbase + s1, TT, Vs[1 - cur], w * 16 + c * 8, lane);
      }
    }

    // ---- scores: wave tile 32t x 64s (2x4 frags)
    f32x4 sacc[2][4] = {};
    #pragma unroll
    for (int ks = 0; ks < 2; ++ks) {
      bfrag kf[4];
      #pragma unroll
      for (int fn = 0; fn < 4; ++fn)
        kf[fn] = *fragp(Ks[cur], fn * 16 + l16, ks * 32 + quad * 8);
      #pragma unroll
      for (int fm = 0; fm < 2; ++fm)
        #pragma unroll
        for (int fn = 0; fn < 4; ++fn)
          sacc[fm][fn] = mfma_bf16(qf[fm][ks], kf[fn], sacc[fm][fn]);
    }

    // ---- p = exp(s/8); row-sum partials; P -> own LDS rows (no barrier)
    #pragma unroll
    for (int fm = 0; fm < 2; ++fm)
      #pragma unroll
      for (int fn = 0; fn < 4; ++fn)
        #pragma unroll
        for (int r = 0; r < 4; ++r) {
          const float p = __expf(sacc[fm][fn][r] * 0.125f);
          lpart[fm][r] += p;
          QP[swze(w * 32 + fm * 16 + quad * 4 + r, fn * 16 + l16)] = (__bf16)p;
        }

    // ---- O += P*V : wave tile 32t x 64d, same-wave P rows
    #pragma unroll
    for (int ks = 0; ks < 2; ++ks) {
      bfrag pf[2], vf[4];
      #pragma unroll
      for (int fm = 0; fm < 2; ++fm)
        pf[fm] = *fragp(QP, w * 32 + fm * 16 + l16, ks * 32 + quad * 8);
      #pragma unroll
      for (int fn = 0; fn < 4; ++fn)
        vf[fn] = *fragp(Vs[cur], fn * 16 + l16, ks * 32 + quad * 8);
      #pragma unroll
      for (int fm = 0; fm < 2; ++fm)
        #pragma unroll
        for (int fn = 0; fn < 4; ++fn)
          oacc[fm][fn] = mfma_bf16(pf[fm], vf[fn], oacc[fm][fn]);
    }
  }

  // ---- row sums: butterfly over the 16 cols held across l16 lanes
  float linvv[2][4];
  #pragma unroll
  for (int fm = 0; fm < 2; ++fm)
    #pragma unroll
    for (int r = 0; r < 4; ++r) {
      float v = lpart[fm][r];
      v += __shfl_xor(v, 1, 16);
      v += __shfl_xor(v, 2, 16);
      v += __shfl_xor(v, 4, 16);
      v += __shfl_xor(v, 8, 16);
      linvv[fm][r] = 1.0f / v;
    }
  if (l16 == 0) {
    #pragma unroll
    for (int fm = 0; fm < 2; ++fm)
      #pragma unroll
      for (int r = 0; r < 4; ++r)
        linv_ws[bh * TT + t0 + w * 32 + fm * 16 + quad * 4 + r] = linvv[fm][r];
  }

  #pragma unroll
  for (int fm = 0; fm < 2; ++fm)
    #pragma unroll
    for (int r = 0; r < 4; ++r) {
      const int row = w * 32 + fm * 16 + quad * 4 + r;
      #pragma unroll
      for (int fn = 0; fn < 4; ++fn) {
        const int d = fn * 16 + l16;
        ob[((size_t)(t0 + row) * BBATCH + b) * EE + h * HD + d] =
            (__bf16)(oacc[fm][fn][r] * linvv[fm][r]);
      }
    }
}

// ---------------- avg_w: mean over heads of softmax probs ----------------
// t-tile 128 x s-tile 64, loop h. Q+K double-buffered over h, one barrier
// per h, zero epilogue barriers. Wave w owns 32 t-rows x all 64 s.
// grid (TT/64, TT/128, B) = 1024 blocks.
__global__ __launch_bounds__(256) void avg_attn(const __bf16* __restrict__ qb,
                                                const __bf16* __restrict__ kb,
                                                const float* __restrict__ linv_ws,
                                                float* __restrict__ avg_out) {
  __shared__ __bf16 Qs[2][128 * 64];   // 2 x 16KB
  __shared__ __bf16 Ks2[2][64 * 64];   // 2 x 8KB

  const int tid = threadIdx.x, lane = tid & 63, w = tid >> 6;
  const int quad = lane >> 4, l16 = lane & 15;
  const int s0 = blockIdx.x * 64, t0 = blockIdx.y * 128;
  const int b = blockIdx.z;

  // stage h = 0
  {
    const size_t bh0 = (size_t)b * HN;
    #pragma unroll
    for (int c = 0; c < 4; ++c)
      stage8(qb + (bh0 * TT + t0) * HD, HD, Qs[0], w * 32 + c * 8, lane);
    #pragma unroll
    for (int c = 0; c < 2; ++c)
      stage8(kb + (bh0 * TT + s0) * HD, HD, Ks2[0], w * 16 + c * 8, lane);
  }

  f32x4 aacc[2][4] = {};

  for (int h = 0; h < HN; ++h) {
    const int cur = h & 1;
    const size_t bh = (size_t)(b * HN + h);
    __syncthreads();   // buf[cur] staged
    if (h + 1 < HN) {  // prefetch next head
      const size_t bh1 = bh + 1;
      #pragma unroll
      for (int c = 0; c < 4; ++c)
        stage8(qb + (bh1 * TT + t0) * HD, HD, Qs[1 - cur], w * 32 + c * 8, lane);
      #pragma unroll
      for (int c = 0; c < 2; ++c)
        stage8(kb + (bh1 * TT + s0) * HD, HD, Ks2[1 - cur], w * 16 + c * 8, lane);
    }

    f32x4 sacc[2][4] = {};
    #pragma unroll
    for (int ks = 0; ks < 2; ++ks) {
      bfrag qf[2], kf[4];
      #pragma unroll
      for (int fm = 0; fm < 2; ++fm)
        qf[fm] = *fragp(Qs[cur], w * 32 + fm * 16 + l16, ks * 32 + quad * 8);
      #pragma unroll
      for (int fn = 0; fn < 4; ++fn)
        kf[fn] = *fragp(Ks2[cur], fn * 16 + l16, ks * 32 + quad * 8);
      #pragma unroll
      for (int fm = 0; fm < 2; ++fm)
        #pragma unroll
        for (int fn = 0; fn < 4; ++fn)
          sacc[fm][fn] = mfma_bf16(qf[fm], kf[fn], sacc[fm][fn]);
    }

    float lv[2][4];
    #pragma unroll
    for (int fm = 0; fm < 2; ++fm)
      #pragma unroll
      for (int r = 0; r < 4; ++r)
        lv[fm][r] = linv_ws[bh * TT + t0 + w * 32 + fm * 16 + quad * 4 + r];

    #pragma unroll
    for (int fm = 0; fm < 2; ++fm)
      #pragma unroll
      for (int fn = 0; fn < 4; ++fn)
        #pragma unroll
        for (int r = 0; r < 4; ++r)
          aacc[fm][fn][r] += __expf(sacc[fm][fn][r] * 0.125f) * lv[fm][r];
  }

  const float invh = 1.0f / (float)HN;
  #pragma unroll
  for (int fm = 0; fm < 2; ++fm)
    #pragma unroll
    for (int r = 0; r < 4; ++r) {
      const int t = t0 + w * 32 + fm * 16 + quad * 4 + r;
      #pragma unroll
      for (int fn = 0; fn < 4; ++fn) {
        const int s = s0 + fn * 16 + l16;
        avg_out[((size_t)b * TT + t) * TT + s] = aacc[fm][fn][r] * invh;
      }
    }
}

extern "C" void kernel_launch(void* const* d_in, const int* in_sizes, int n_in,
                              void* d_out, int out_size, void* d_ws, size_t ws_size,
                              hipStream_t stream) {
  (void)in_sizes; (void)n_in; (void)out_size; (void)ws_size;
  const float* query = (const float*)d_in[0];
  const float* key   = (const float*)d_in[1];
  const float* value = (const float*)d_in[2];
  const float* Wq = (const float*)d_in[3];
  const float* bq = (const float*)d_in[4];
  const float* Wk = (const float*)d_in[5];
  const float* bk = (const float*)d_in[6];
  const float* Wv = (const float*)d_in[7];
  const float* bv = (const float*)d_in[8];
  const float* Wo = (const float*)d_in[9];
  const float* bo = (const float*)d_in[10];

  char* ws = (char*)d_ws;
  size_t off = 0;
  auto wsalloc = [&](size_t bytes) -> void* {
    void* p = ws + off;
    off += (bytes + 255) & ~(size_t)255;
    return p;
  };
  const size_t XE = (size_t)MM * EE;        // 4,194,304 elems
  const size_t WE = (size_t)EE * EE;        // 1,048,576 elems
  __bf16* xq   = (__bf16*)wsalloc(XE * 2);
  __bf16* xk   = (__bf16*)wsalloc(XE * 2);
  __bf16* xv   = (__bf16*)wsalloc(XE * 2);
  __bf16* wqb  = (__bf16*)wsalloc(WE * 2);
  __bf16* wkb  = (__bf16*)wsalloc(WE * 2);
  __bf16* wvb  = (__bf16*)wsalloc(WE * 2);
  __bf16* wob  = (__bf16*)wsalloc(WE * 2);
  __bf16* qbuf = (__bf16*)wsalloc(XE * 2);
  __bf16* kbuf = (__bf16*)wsalloc(XE * 2);
  __bf16* vtbuf= (__bf16*)wsalloc(XE * 2);
  __bf16* obuf = (__bf16*)wsalloc(XE * 2);
  float* linv  = (float*)wsalloc((size_t)BBATCH * HN * TT * 4);
  // total ~64.3 MB of ws

  CvtArgs ca;
  ca.src[0] = query; ca.dst[0] = xq;  ca.n4[0] = (int)(XE / 4);
  ca.src[1] = key;   ca.dst[1] = xk;  ca.n4[1] = (int)(XE / 4);
  ca.src[2] = value; ca.dst[2] = xv;  ca.n4[2] = (int)(XE / 4);
  ca.src[3] = Wq;    ca.dst[3] = wqb; ca.n4[3] = (int)(WE / 4);
  ca.src[4] = Wk;    ca.dst[4] = wkb; ca.n4[4] = (int)(WE / 4);
  ca.src[5] = Wv;    ca.dst[5] = wvb; ca.n4[5] = (int)(WE / 4);
  ca.src[6] = Wo;    ca.dst[6] = wob; ca.n4[6] = (int)(WE / 4);
  cvt_all<<<dim3(4096, 1, 7), 256, 0, stream>>>(ca);

  gemm_qkv<<<dim3(8, 32, 3), 256, 0, stream>>>(xq, xk, xv, wqb, wkb, wvb,
                                               bq, bk, bv, qbuf, kbuf, vtbuf);

  attn_fwd<<<dim3(16, HN, BBATCH), 256, 0, stream>>>(qbuf, kbuf, vtbuf, obuf, linv);

  float* avg_out = (float*)d_out + (size_t)TT * BBATCH * EE;
  avg_attn<<<dim3(32, 16, 2), 256, 0, stream>>>(qbuf, kbuf, linv, avg_out);

  gemm_o64<<<dim3(8, 64), 256, 0, stream>>>(obuf, wob, bo, (float*)d_out);
}